// Round 6
// baseline (482.961 us; speedup 1.0000x reference)
//
#include <hip/hip_runtime.h>

#define BATCH 1024
#define SEQ   144
#define DIM   192
#define NH    6
#define HD    32
#define SCALE 0.17677669529663687f  // 1/sqrt(32)

typedef __bf16 bf16x8 __attribute__((ext_vector_type(8)));
typedef __bf16 bf16x4 __attribute__((ext_vector_type(4)));
typedef float  f32x4  __attribute__((ext_vector_type(4)));

// ---- workspace layout (bytes) ----
#define WS_W1T   0          // bf16 [576][192]  w1t[c][k] = w1[k][c] (*SCALE for c<192)
#define WS_W2T   221184     // bf16 [192][192]  w2t[n][k] = w2[k][n]
#define WS_B1S   294912     // f32  [576]       b1 (*SCALE for c<192)
#define WS_BM    297216     // bf16 [6][144][144]  bm[h][query][key] = bias + mask
#define WS_QF    546048     // bf16 [1024*6][144][32]  q (scaled, biased); later opre
#define WS_KF    57169152   // bf16 [1024*6][144][32]  k (biased)
#define WS_VT    113792256  // bf16 [1024*6][32][144]  v^T (biased)
#define WS_DEC_NEED 170415360ull
#define WS_MID_NEED 57169152ull

// ---------------------------------------------------------------------------
// Prep: transpose/convert weights to bf16 B^T layout, build bf16 bias+mask.
// ---------------------------------------------------------------------------
__global__ __launch_bounds__(256) void k_prep(
        const float* __restrict__ w1, const float* __restrict__ w2,
        const float* __restrict__ b1, const float* __restrict__ bt,
        const int* __restrict__ pidx, const int* __restrict__ mask,
        char* __restrict__ ws) {
    __bf16* w1t = (__bf16*)(ws + WS_W1T);
    __bf16* w2t = (__bf16*)(ws + WS_W2T);
    float*  b1s = (float*)(ws + WS_B1S);
    __bf16* bm  = (__bf16*)(ws + WS_BM);
    const int blk = blockIdx.x, t = threadIdx.x;
    if (blk < 432) {                       // w1t: 110592 elems
        int idx = blk * 256 + t;
        int k = idx / 576, c = idx % 576;
        float v = w1[idx] * (c < 192 ? SCALE : 1.0f);
        w1t[c * 192 + k] = (__bf16)v;
    } else if (blk < 576) {                // w2t: 36864 elems
        int idx = (blk - 432) * 256 + t;
        int k = idx / 192, n = idx % 192;
        w2t[n * 192 + k] = (__bf16)w2[idx];
    } else if (blk < 657) {                // bm: 20736 (query,key) pairs
        int idx = (blk - 576) * 256 + t;   // idx = query*144 + key
        int p = pidx[idx];
        float add = (mask[idx] == 0) ? -1e9f : 0.0f;
#pragma unroll
        for (int h = 0; h < NH; ++h)
            bm[h * 20736 + idx] = (__bf16)(bt[p * NH + h] + add);
    } else {                               // b1s
        for (int c = t; c < 576; c += 256)
            b1s[c] = b1[c] * (c < 192 ? SCALE : 1.0f);
    }
}

// ---------------------------------------------------------------------------
// QKV GEMM: y[147456,576] = x(bf16) @ w1t^T (+b1s), scattered to q/k/v^T.
// 2304 blocks x 512 thr (8 waves = 4 row-strips x 2 col-halves).
// A staged in LDS; B-frags from L2 (k_proj-proven pattern, 18 indep chains).
// v is written TRANSPOSED (free in epilogue) for the attention PV B-operand.
// ---------------------------------------------------------------------------
__global__ __launch_bounds__(512) void k_qkv(
        const float* __restrict__ x, char* __restrict__ ws) {
    const __bf16* w1t = (const __bf16*)(ws + WS_W1T);
    const float*  b1s = (const float*)(ws + WS_B1S);
    __bf16* qf  = (__bf16*)(ws + WS_QF);
    __bf16* kf  = (__bf16*)(ws + WS_KF);
    __bf16* vtf = (__bf16*)(ws + WS_VT);

    __shared__ __bf16 As[64 * 200];
    const int tid  = threadIdx.x;
    const size_t row0 = (size_t)blockIdx.x * 64;

    // stage X rows -> bf16 LDS [64][200]
#pragma unroll
    for (int it = 0; it < 6; ++it) {
        int i = tid + it * 512;               // 3072 f32x4 chunks
        int row = i / 48, c4 = (i % 48) * 4;
        f32x4 v = *(const f32x4*)&x[(row0 + row) * DIM + c4];
        bf16x4 pk;
        pk[0] = (__bf16)v[0]; pk[1] = (__bf16)v[1];
        pk[2] = (__bf16)v[2]; pk[3] = (__bf16)v[3];
        *(bf16x4*)&As[row * 200 + c4] = pk;
    }
    __syncthreads();

    const int w = tid >> 6, lr = tid & 15, lg = (tid & 63) >> 4;
    const int strip = w >> 1, ch = w & 1;     // 4 row-strips x 2 col-halves
    const f32x4 zf = {0.f, 0.f, 0.f, 0.f};
    f32x4 acc[18];
#pragma unroll
    for (int t = 0; t < 18; ++t) acc[t] = zf;

#pragma unroll
    for (int kk = 0; kk < 6; ++kk) {
        bf16x8 aF = *(bf16x8*)&As[(strip * 16 + lr) * 200 + kk * 32 + lg * 8];
#pragma unroll
        for (int t = 0; t < 18; ++t) {
            bf16x8 bF = *(const bf16x8*)(w1t +
                ((size_t)((ch * 18 + t) * 16 + lr) * 192 + kk * 32 + lg * 8));
            acc[t] = __builtin_amdgcn_mfma_f32_16x16x32_bf16(aF, bF, acc[t], 0, 0, 0);
        }
    }

    // epilogue: +bias, scatter to q / k / v^T
    const int grow0 = (int)row0 + strip * 16 + lg * 4;   // 4-row group, same b
    const int b = grow0 / 144, m = grow0 - b * 144;
#pragma unroll
    for (int t = 0; t < 18; ++t) {
        int tile = ch * 18 + t;
        int g = tile / 12, nn = tile % 12;
        int h = nn >> 1, j = (nn & 1) * 16 + lr;
        float bb = b1s[tile * 16 + lr];
        size_t hb = (size_t)(b * NH + h);
        if (g == 0) {
            __bf16* d = qf + (hb * SEQ + m) * HD + j;
#pragma unroll
            for (int r = 0; r < 4; ++r) d[r * HD] = (__bf16)(acc[t][r] + bb);
        } else if (g == 1) {
            __bf16* d = kf + (hb * SEQ + m) * HD + j;
#pragma unroll
            for (int r = 0; r < 4; ++r) d[r * HD] = (__bf16)(acc[t][r] + bb);
        } else {
            bf16x4 pk;
#pragma unroll
            for (int r = 0; r < 4; ++r) pk[r] = (__bf16)(acc[t][r] + bb);
            *(bf16x4*)&vtf[(hb * HD + j) * SEQ + m] = pk;
        }
    }
}

// ---------------------------------------------------------------------------
// Attention per (b,h), decoupled: K/Q frags + bias direct from global
// (coalesced bf16), V^T staged to LDS. ONE barrier. LDS 21.2 KB.
// opre aliases qf: each wave reads then overwrites only its own 16 rows.
// ---------------------------------------------------------------------------
__global__ __launch_bounds__(576) void k_attn2(char* __restrict__ ws) {
    const __bf16* bmB = (const __bf16*)(ws + WS_BM);
    const __bf16* qf  = (const __bf16*)(ws + WS_QF);
    const __bf16* kf  = (const __bf16*)(ws + WS_KF);
    const __bf16* vtf = (const __bf16*)(ws + WS_VT);
    __bf16* opre = (__bf16*)(ws + WS_QF);   // alias (safe: wave-private rows)

    __shared__ char smem[21248];
    __bf16* Vt  = (__bf16*)smem;             // [32][152]  9728 B
    __bf16* Pws = (__bf16*)(smem + 9728);    // 9 x [16][40] wave-private

    const int bx = blockIdx.x;
    const int b = bx / NH, h = bx % NH;
    const size_t hb = (size_t)(b * NH + h);

    const int tid = threadIdx.x;
    const int w   = tid >> 6;
    const int lr  = tid & 15;
    const int lg  = (tid & 63) >> 4;
    const int m0  = w * 16;
    const f32x4 zf = {0.f, 0.f, 0.f, 0.f};
    const bf16x8 zb = {(__bf16)0.f,(__bf16)0.f,(__bf16)0.f,(__bf16)0.f,
                       (__bf16)0.f,(__bf16)0.f,(__bf16)0.f,(__bf16)0.f};

    // ---- issue Vt stage load (1 chunk per thread: 576 = 32*18)
    const int srow = tid / 18, sc = tid % 18;
    bf16x8 vstage = *(const bf16x8*)(vtf + hb * (HD * SEQ) + srow * SEQ + sc * 8);

    // ---- QK^T (swapped): st[i] = S[key tile i][query m0+lr]
    bf16x8 qF = *(const bf16x8*)(qf + (hb * SEQ + m0 + lr) * HD + lg * 8);
    f32x4 st[9];
#pragma unroll
    for (int i = 0; i < 9; ++i) {
        bf16x8 aF = *(const bf16x8*)(kf + (hb * SEQ + i * 16 + lr) * HD + lg * 8);
        st[i] = __builtin_amdgcn_mfma_f32_16x16x32_bf16(aF, qF, zf, 0, 0, 0);
    }
    *(bf16x8*)&Vt[srow * 152 + sc * 8] = vstage;   // ds_write (stage complete)

    // ---- bias + in-register softmax
    {
        const __bf16* bmh = bmB + h * 20736 + (m0 + lr) * SEQ;
        float mx = -3.0e38f;
#pragma unroll
        for (int i = 0; i < 9; ++i) {
            bf16x4 bb = *(const bf16x4*)&bmh[i * 16 + lg * 4];
#pragma unroll
            for (int r = 0; r < 4; ++r) {
                st[i][r] += (float)bb[r];
                mx = fmaxf(mx, st[i][r]);
            }
        }
        mx = fmaxf(mx, __shfl_xor(mx, 16));
        mx = fmaxf(mx, __shfl_xor(mx, 32));
        float sum = 0.f;
#pragma unroll
        for (int i = 0; i < 9; ++i)
#pragma unroll
            for (int r = 0; r < 4; ++r) {
                float e = __expf(st[i][r] - mx);
                st[i][r] = e;
                sum += e;
            }
        sum += __shfl_xor(sum, 16);
        sum += __shfl_xor(sum, 32);
        float inv = 1.f / sum;
#pragma unroll
        for (int i = 0; i < 9; ++i)
#pragma unroll
            for (int r = 0; r < 4; ++r) st[i][r] *= inv;
    }
    __syncthreads();   // Vt visible (the only barrier)

    // ---- PV via per-wave chunked P scratch
    __bf16* Pw = Pws + w * 640;    // [16][40]
    f32x4 o0 = zf, o1 = zf;
#pragma unroll
    for (int s = 0; s < 4; ++s) {
#pragma unroll
        for (int d = 0; d < 2; ++d) {
            int ii = 2 * s + d;
            bf16x4 pk;
#pragma unroll
            for (int r = 0; r < 4; ++r) pk[r] = (__bf16)st[ii][r];
            *(bf16x4*)&Pw[lr * 40 + d * 16 + lg * 4] = pk;
        }
        bf16x8 aP  = *(bf16x8*)&Pw[lr * 40 + lg * 8];
        bf16x8 v0F = *(bf16x8*)&Vt[lr * 152 + s * 32 + lg * 8];
        bf16x8 v1F = *(bf16x8*)&Vt[(16 + lr) * 152 + s * 32 + lg * 8];
        o0 = __builtin_amdgcn_mfma_f32_16x16x32_bf16(aP, v0F, o0, 0, 0, 0);
        o1 = __builtin_amdgcn_mfma_f32_16x16x32_bf16(aP, v1F, o1, 0, 0, 0);
    }
    {   // tail keys 128..143: lanes lg>=2 supply zeros
        bf16x4 pk;
#pragma unroll
        for (int r = 0; r < 4; ++r) pk[r] = (__bf16)st[8][r];
        *(bf16x4*)&Pw[lr * 40 + lg * 4] = pk;
        bf16x8 aP = zb, v0F = zb, v1F = zb;
        if (lg < 2) {
            aP  = *(bf16x8*)&Pw[lr * 40 + lg * 8];
            v0F = *(bf16x8*)&Vt[lr * 152 + 128 + lg * 8];
            v1F = *(bf16x8*)&Vt[(16 + lr) * 152 + 128 + lg * 8];
        }
        o0 = __builtin_amdgcn_mfma_f32_16x16x32_bf16(aP, v0F, o0, 0, 0, 0);
        o1 = __builtin_amdgcn_mfma_f32_16x16x32_bf16(aP, v1F, o1, 0, 0, 0);
    }

    // ---- O restage (coalesce) + store to opre[b,h,m,32] (== qf rows, own wave)
#pragma unroll
    for (int r = 0; r < 4; ++r) {
        Pw[(lg * 4 + r) * 40 + lr]      = (__bf16)o0[r];
        Pw[(lg * 4 + r) * 40 + 16 + lr] = (__bf16)o1[r];
    }
    {
        int l = tid & 63;
        int row = l >> 2, c = l & 3;
        bf16x8 ov = *(bf16x8*)&Pw[row * 40 + c * 8];
        *(bf16x8*)&opre[(hb * SEQ + m0 + row) * HD + c * 8] = ov;
    }
}

// ---------------------------------------------------------------------------
// Fused fallback (ws in [57MB,170MB)): round-4 per-(b,h) kernel, Ws staged,
// opre written in h-major layout [b,h,m,32].
// ---------------------------------------------------------------------------
__global__ __launch_bounds__(576, 4) void k_attn_mid(
        const float* __restrict__ x, const char* __restrict__ ws,
        __bf16* __restrict__ opre) {
    const __bf16* w1t = (const __bf16*)(ws + WS_W1T);
    const float*  b1s = (const float*)(ws + WS_B1S);
    const __bf16* bmB = (const __bf16*)(ws + WS_BM);

    __shared__ char smem[71168];
    __bf16* Ws = (__bf16*)(smem);            // [96][200]
    __bf16* Ks = (__bf16*)(smem + 38400);    // [144][40]
    __bf16* Vt = (__bf16*)(smem + 49920);    // [32][152]
    __bf16* Qs = (__bf16*)(smem + 59648);    // [144][40] wave-private overlay

    const int swz = (blockIdx.x & 7) * 768 + (blockIdx.x >> 3);
    const int b = swz / NH;
    const int h = swz % NH;

    const int tid = threadIdx.x;
    const int w   = tid >> 6;
    const int lr  = tid & 15;
    const int lg  = (tid & 63) >> 4;
    const int m0  = w * 16;
    const f32x4 zf = {0.f, 0.f, 0.f, 0.f};
    const bf16x8 zb = {(__bf16)0.f,(__bf16)0.f,(__bf16)0.f,(__bf16)0.f,
                       (__bf16)0.f,(__bf16)0.f,(__bf16)0.f,(__bf16)0.f};

#pragma unroll
    for (int it = 0; it < 4; ++it) {
        int idx = tid + it * 576;
        int r = idx / 24, c = idx % 24;
        int tt = r >> 5, j = r & 31;
        bf16x8 v = *(const bf16x8*)(w1t + ((tt * 192 + h * 32 + j) * 192 + c * 8));
        *(bf16x8*)&Ws[r * 200 + c * 8] = v;
    }
    bf16x8 aX[6];
    {
        const float* xr = x + ((size_t)b * SEQ + m0 + lr) * DIM + lg * 8;
#pragma unroll
        for (int kk = 0; kk < 6; ++kk) {
            f32x4 u = *(const f32x4*)(xr + kk * 32);
            f32x4 v = *(const f32x4*)(xr + kk * 32 + 4);
            bf16x8 t;
            t[0]=(__bf16)u[0]; t[1]=(__bf16)u[1]; t[2]=(__bf16)u[2]; t[3]=(__bf16)u[3];
            t[4]=(__bf16)v[0]; t[5]=(__bf16)v[1]; t[6]=(__bf16)v[2]; t[7]=(__bf16)v[3];
            aX[kk] = t;
        }
    }
    __syncthreads();

    {
        f32x4 acc[6];
#pragma unroll
        for (int n = 0; n < 6; ++n) acc[n] = zf;
#pragma unroll
        for (int kk = 0; kk < 6; ++kk) {
#pragma unroll
            for (int n = 0; n < 6; ++n) {
                bf16x8 bF = *(bf16x8*)&Ws[(n * 16 + lr) * 200 + kk * 32 + lg * 8];
                acc[n] = __builtin_amdgcn_mfma_f32_16x16x32_bf16(aX[kk], bF, acc[n], 0, 0, 0);
            }
        }
#pragma unroll
        for (int n = 0; n < 6; ++n) {
            int j = (n & 1) * 16 + lr;
            float bb = b1s[(n >> 1) * 192 + h * 32 + j];
            if (n < 2) {
#pragma unroll
                for (int r = 0; r < 4; ++r)
                    Qs[(m0 + lg * 4 + r) * 40 + j] = (__bf16)(acc[n][r] + bb);
            } else if (n < 4) {
#pragma unroll
                for (int r = 0; r < 4; ++r)
                    Ks[(m0 + lg * 4 + r) * 40 + j] = (__bf16)(acc[n][r] + bb);
            } else {
                bf16x4 pk;
#pragma unroll
                for (int r = 0; r < 4; ++r) pk[r] = (__bf16)(acc[n][r] + bb);
                *(bf16x4*)&Vt[j * 152 + m0 + lg * 4] = pk;
            }
        }
    }
    __syncthreads();

    f32x4 st[9];
    {
        bf16x8 qF = *(bf16x8*)&Qs[(m0 + lr) * 40 + lg * 8];
#pragma unroll
        for (int i = 0; i < 9; ++i) {
            bf16x8 aF = *(bf16x8*)&Ks[(i * 16 + lr) * 40 + lg * 8];
            st[i] = __builtin_amdgcn_mfma_f32_16x16x32_bf16(aF, qF, zf, 0, 0, 0);
        }
        const __bf16* bmh = bmB + h * 20736 + (m0 + lr) * SEQ;
        float mx = -3.0e38f;
#pragma unroll
        for (int i = 0; i < 9; ++i) {
            bf16x4 bb = *(const bf16x4*)&bmh[i * 16 + lg * 4];
#pragma unroll
            for (int r = 0; r < 4; ++r) {
                st[i][r] += (float)bb[r];
                mx = fmaxf(mx, st[i][r]);
            }
        }
        mx = fmaxf(mx, __shfl_xor(mx, 16));
        mx = fmaxf(mx, __shfl_xor(mx, 32));
        float sum = 0.f;
#pragma unroll
        for (int i = 0; i < 9; ++i)
#pragma unroll
            for (int r = 0; r < 4; ++r) {
                float e = __expf(st[i][r] - mx);
                st[i][r] = e;
                sum += e;
            }
        sum += __shfl_xor(sum, 16);
        sum += __shfl_xor(sum, 32);
        float inv = 1.f / sum;
#pragma unroll
        for (int i = 0; i < 9; ++i)
#pragma unroll
            for (int r = 0; r < 4; ++r) st[i][r] *= inv;
    }

    __bf16* Pw = Qs + m0 * 40;
    f32x4 o0 = zf, o1 = zf;
#pragma unroll
    for (int s = 0; s < 4; ++s) {
#pragma unroll
        for (int d = 0; d < 2; ++d) {
            int ii = 2 * s + d;
            bf16x4 pk;
#pragma unroll
            for (int r = 0; r < 4; ++r) pk[r] = (__bf16)st[ii][r];
            *(bf16x4*)&Pw[lr * 40 + d * 16 + lg * 4] = pk;
        }
        bf16x8 aP  = *(bf16x8*)&Pw[lr * 40 + lg * 8];
        bf16x8 v0F = *(bf16x8*)&Vt[lr * 152 + s * 32 + lg * 8];
        bf16x8 v1F = *(bf16x8*)&Vt[(16 + lr) * 152 + s * 32 + lg * 8];
        o0 = __builtin_amdgcn_mfma_f32_16x16x32_bf16(aP, v0F, o0, 0, 0, 0);
        o1 = __builtin_amdgcn_mfma_f32_16x16x32_bf16(aP, v1F, o1, 0, 0, 0);
    }
    {
        bf16x4 pk;
#pragma unroll
        for (int r = 0; r < 4; ++r) pk[r] = (__bf16)st[8][r];
        *(bf16x4*)&Pw[lr * 40 + lg * 4] = pk;
        bf16x8 aP = zb, v0F = zb, v1F = zb;
        if (lg < 2) {
            aP  = *(bf16x8*)&Pw[lr * 40 + lg * 8];
            v0F = *(bf16x8*)&Vt[lr * 152 + 128 + lg * 8];
            v1F = *(bf16x8*)&Vt[(16 + lr) * 152 + 128 + lg * 8];
        }
        o0 = __builtin_amdgcn_mfma_f32_16x16x32_bf16(aP, v0F, o0, 0, 0, 0);
        o1 = __builtin_amdgcn_mfma_f32_16x16x32_bf16(aP, v1F, o1, 0, 0, 0);
    }

#pragma unroll
    for (int r = 0; r < 4; ++r) {
        Pw[(lg * 4 + r) * 40 + lr]      = (__bf16)o0[r];
        Pw[(lg * 4 + r) * 40 + 16 + lr] = (__bf16)o1[r];
    }
    {
        int l = tid & 63;
        int row = l >> 2, c = l & 3;
        bf16x8 ov = *(bf16x8*)&Pw[row * 40 + c * 8];
        *(bf16x8*)&opre[(((size_t)b * NH + h) * SEQ + m0 + row) * HD + c * 8] = ov;
    }
}

// ---------------------------------------------------------------------------
// Out-projection: out[147456,192] = opre(bf16, h-major [b,h,m,32]) @ w2 + b2.
// ---------------------------------------------------------------------------
__global__ __launch_bounds__(256, 4) void k_proj(
        const __bf16* __restrict__ opre, const char* __restrict__ ws,
        const float* __restrict__ b2, float* __restrict__ out) {
    const __bf16* w2t = (const __bf16*)(ws + WS_W2T);
    __shared__ __bf16 As[64][200];
    const int tid = threadIdx.x;
    const size_t row0 = (size_t)blockIdx.x * 64;

#pragma unroll
    for (int it = 0; it < 6; ++it) {
        int i = tid + it * 256;              // 1536 16B chunks
        int lrow = i / 24, c8 = i % 24;
        int grow = (int)row0 + lrow;
        int b = grow / 144, m = grow - b * 144;
        int h = c8 / 4, col32 = (c8 & 3) * 8;
        *(bf16x8*)&As[lrow][c8 * 8] =
            *(const bf16x8*)&opre[(((size_t)b * NH + h) * SEQ + m) * HD + col32];
    }
    __syncthreads();

    const int w  = tid >> 6;
    const int lr = tid & 15;
    const int lg = (tid & 63) >> 4;
    const f32x4 zf = {0.f, 0.f, 0.f, 0.f};
    f32x4 oa[12];
#pragma unroll
    for (int n = 0; n < 12; ++n) oa[n] = zf;

#pragma unroll
    for (int kk = 0; kk < 6; ++kk) {
        bf16x8 aF = *(bf16x8*)&As[w * 16 + lr][kk * 32 + lg * 8];
#pragma unroll
        for (int n = 0; n < 12; ++n) {
            bf16x8 bW = *(const bf16x8*)(w2t + ((n * 16 + lr) * 192 + kk * 32 + lg * 8));
            oa[n] = __builtin_amdgcn_mfma_f32_16x16x32_bf16(aF, bW, oa[n], 0, 0, 0);
        }
    }
#pragma unroll
    for (int n = 0; n < 12; ++n) {
        int col = n * 16 + lr;
        float bb = b2[col];
#pragma unroll
        for (int r = 0; r < 4; ++r)
            out[(row0 + w * 16 + lg * 4 + r) * DIM + col] = oa[n][r] + bb;
    }
}

// ---------------------------------------------------------------------------
extern "C" void kernel_launch(void* const* d_in, const int* in_sizes, int n_in,
                              void* d_out, int out_size, void* d_ws, size_t ws_size,
                              hipStream_t stream) {
    const float* x    = (const float*)d_in[0];
    const float* w1   = (const float*)d_in[1];
    const float* b1   = (const float*)d_in[2];
    const float* w2   = (const float*)d_in[3];
    const float* b2   = (const float*)d_in[4];
    const float* bt   = (const float*)d_in[5];
    const int*   pidx = (const int*)d_in[6];
    const int*   mask = (const int*)d_in[7];
    float* out = (float*)d_out;
    char*  ws  = (char*)d_ws;
    __bf16* opre = (__bf16*)(ws + WS_QF);

    k_prep<<<658, 256, 0, stream>>>(w1, w2, b1, bt, pidx, mask, ws);
    if (ws_size >= WS_DEC_NEED) {
        k_qkv<<<(BATCH * SEQ) / 64, 512, 0, stream>>>(x, ws);
        k_attn2<<<BATCH * NH, 576, 0, stream>>>(ws);
    } else {
        k_attn_mid<<<BATCH * NH, 576, 0, stream>>>(x, ws, opre);
    }
    k_proj<<<(BATCH * SEQ) / 64, 256, 0, stream>>>(opre, ws, b2, out);
}

// Round 7
// 230.539 us; speedup vs baseline: 2.0949x; 2.0949x over previous
//
#include <hip/hip_runtime.h>

#define BATCH 1024
#define SEQ   144
#define DIM   192
#define NH    6
#define HD    32
#define SCALE 0.17677669529663687f  // 1/sqrt(32)

typedef __bf16 bf16x8 __attribute__((ext_vector_type(8)));
typedef __bf16 bf16x4 __attribute__((ext_vector_type(4)));
typedef float  f32x4  __attribute__((ext_vector_type(4)));

// ---- workspace layout (bytes) ----
#define WS_W1T   0          // bf16 [576][192]  w1t[c][k] = w1[k][c] (*SCALE for c<192)
#define WS_W2T   221184     // bf16 [192][192]  w2t[n][k] = w2[k][n]
#define WS_B1S   294912     // f32  [576]       b1 (*SCALE for c<192)
#define WS_BM    297216     // bf16 [6][144][144]  bm[h][query][key] = bias + mask
#define WS_OPRE  546048     // bf16 [1024][144][192] pre-projection attention output

// ---------------------------------------------------------------------------
// Prep: transpose/convert weights to bf16 B^T layout, build bf16 bias+mask.
// ---------------------------------------------------------------------------
__global__ __launch_bounds__(256) void k_prep(
        const float* __restrict__ w1, const float* __restrict__ w2,
        const float* __restrict__ b1, const float* __restrict__ bt,
        const int* __restrict__ pidx, const int* __restrict__ mask,
        char* __restrict__ ws) {
    __bf16* w1t = (__bf16*)(ws + WS_W1T);
    __bf16* w2t = (__bf16*)(ws + WS_W2T);
    float*  b1s = (float*)(ws + WS_B1S);
    __bf16* bm  = (__bf16*)(ws + WS_BM);
    const int blk = blockIdx.x, t = threadIdx.x;
    if (blk < 432) {                       // w1t: 110592 elems
        int idx = blk * 256 + t;
        int k = idx / 576, c = idx % 576;
        float v = w1[idx] * (c < 192 ? SCALE : 1.0f);
        w1t[c * 192 + k] = (__bf16)v;
    } else if (blk < 576) {                // w2t: 36864 elems
        int idx = (blk - 432) * 256 + t;
        int k = idx / 192, n = idx % 192;
        w2t[n * 192 + k] = (__bf16)w2[idx];
    } else if (blk < 657) {                // bm: 20736 (query,key) pairs
        int idx = (blk - 576) * 256 + t;   // idx = query*144 + key
        int p = pidx[idx];
        float add = (mask[idx] == 0) ? -1e9f : 0.0f;
#pragma unroll
        for (int h = 0; h < NH; ++h)
            bm[h * 20736 + idx] = (__bf16)(bt[p * NH + h] + add);
    } else {                               // b1s
        for (int c = t; c < 576; c += 256)
            b1s[c] = b1[c] * (c < 192 ? SCALE : 1.0f);
    }
}

// ---------------------------------------------------------------------------
// Fused QKV + attention. Block = fixed head h, 8 consecutive b's.
// Grid 768 = 8 XCD x 96, swizzled so the 6 h-blocks of one b-group run
// concurrently on one XCD (share X in L2). Ws staged ONCE per block.
// Ks/Vt double-buffered -> ONE barrier per b. X[b+1] prefetched into regs
// during b's P2/P3. LDS 92416 B. 9 waves, VGPR capped 170.
// ---------------------------------------------------------------------------
__global__ __launch_bounds__(576, 3) void k_attn(
        const float* __restrict__ x, char* __restrict__ ws) {
    const __bf16* w1t = (const __bf16*)(ws + WS_W1T);
    const float*  b1s = (const float*)(ws + WS_B1S);
    const __bf16* bmB = (const __bf16*)(ws + WS_BM);
    __bf16* opre = (__bf16*)(ws + WS_OPRE);

    __shared__ char smem[92416];
    __bf16* Ws  = (__bf16*)(smem);             // [96][200]  38400B (once)
    __bf16* Ks0 = (__bf16*)(smem + 38400);     // [144][40]  x2 dbuf
    __bf16* Ks1 = (__bf16*)(smem + 49920);
    __bf16* Vt0 = (__bf16*)(smem + 61440);     // [32][152]  x2 dbuf
    __bf16* Vt1 = (__bf16*)(smem + 71168);
    __bf16* Qs  = (__bf16*)(smem + 80896);     // [144][40]  wave-private

    // swizzle: physical g -> (h, bgroup) s.t. one b-group's 6 h-blocks
    // land on one XCD at the same time.  768 = 8 XCD x 96.
    const int g  = blockIdx.x;
    const int h  = (g >> 3) % 6;
    const int bg = (g & 7) + 8 * ((g >> 3) / 6);
    const int b0 = bg * 8;

    const int tid = threadIdx.x;
    const int w   = tid >> 6;
    const int lr  = tid & 15;
    const int lg  = (tid & 63) >> 4;
    const int m0  = w * 16;
    const f32x4 zf = {0.f, 0.f, 0.f, 0.f};
    const bf16x8 zb = {(__bf16)0.f,(__bf16)0.f,(__bf16)0.f,(__bf16)0.f,
                       (__bf16)0.f,(__bf16)0.f,(__bf16)0.f,(__bf16)0.f};

    // ---- stage Ws[96][200] once: row r=tt*32+j <- w1t[tt*192+h*32+j][:]
#pragma unroll
    for (int it = 0; it < 4; ++it) {
        int idx = tid + it * 576;              // 2304 16B chunks
        int r = idx / 24, c = idx % 24;
        int tt = r >> 5, j = r & 31;
        *(bf16x8*)&Ws[r * 200 + c * 8] =
            *(const bf16x8*)(w1t + ((tt * 192 + h * 32 + j) * 192 + c * 8));
    }

    // ---- prologue: X[b0] strip -> aX fragments
    bf16x8 aX[6];
    {
        const float* xr = x + ((size_t)b0 * SEQ + m0 + lr) * DIM + lg * 8;
#pragma unroll
        for (int kk = 0; kk < 6; ++kk) {
            f32x4 u = *(const f32x4*)(xr + kk * 32);
            f32x4 v = *(const f32x4*)(xr + kk * 32 + 4);
            bf16x8 t;
            t[0]=(__bf16)u[0]; t[1]=(__bf16)u[1]; t[2]=(__bf16)u[2]; t[3]=(__bf16)u[3];
            t[4]=(__bf16)v[0]; t[5]=(__bf16)v[1]; t[6]=(__bf16)v[2]; t[7]=(__bf16)v[3];
            aX[kk] = t;
        }
    }
    __syncthreads();   // Ws visible

    const __bf16* bmh = bmB + h * 20736 + (m0 + lr) * SEQ;
    const float*  b1h = b1s;   // b1s[(n>>1)*192 + h*32 + j]

#pragma unroll 2
    for (int nb = 0; nb < 8; ++nb) {
        const int b = b0 + nb;
        __bf16* Ks = (nb & 1) ? Ks1 : Ks0;
        __bf16* Vt = (nb & 1) ? Vt1 : Vt0;

        // ---- P1: Y[strip][96] = X @ W1_h^T  (B-frags from LDS)
        f32x4 acc[6];
#pragma unroll
        for (int n = 0; n < 6; ++n) acc[n] = zf;
#pragma unroll
        for (int kk = 0; kk < 6; ++kk)
#pragma unroll
            for (int n = 0; n < 6; ++n) {
                bf16x8 bF = *(bf16x8*)&Ws[(n * 16 + lr) * 200 + kk * 32 + lg * 8];
                acc[n] = __builtin_amdgcn_mfma_f32_16x16x32_bf16(aX[kk], bF, acc[n], 0, 0, 0);
            }

        // ---- issue X[b+1] prefetch (raw f32; convert at loop end)
        f32x4 nx[12];
        if (nb < 7) {
            const float* xr = x + ((size_t)(b + 1) * SEQ + m0 + lr) * DIM + lg * 8;
#pragma unroll
            for (int q = 0; q < 6; ++q) {
                nx[2 * q]     = *(const f32x4*)(xr + q * 32);
                nx[2 * q + 1] = *(const f32x4*)(xr + q * 32 + 4);
            }
        }

        // ---- bias prefetch (L2)
        bf16x4 bb[9];
#pragma unroll
        for (int i = 0; i < 9; ++i) bb[i] = *(const bf16x4*)&bmh[i * 16 + lg * 4];

        // ---- scatter Q/K/Vt (+b1)
#pragma unroll
        for (int n = 0; n < 6; ++n) {
            int j = (n & 1) * 16 + lr;
            float bv = b1h[(n >> 1) * 192 + h * 32 + j];
            if (n < 2) {
#pragma unroll
                for (int r = 0; r < 4; ++r)
                    Qs[(m0 + lg * 4 + r) * 40 + j] = (__bf16)(acc[n][r] + bv);
            } else if (n < 4) {
#pragma unroll
                for (int r = 0; r < 4; ++r)
                    Ks[(m0 + lg * 4 + r) * 40 + j] = (__bf16)(acc[n][r] + bv);
            } else {
                bf16x4 pk;
#pragma unroll
                for (int r = 0; r < 4; ++r) pk[r] = (__bf16)(acc[n][r] + bv);
                *(bf16x4*)&Vt[j * 152 + m0 + lg * 4] = pk;   // [dim][key]
            }
        }
        __syncthreads();   // the ONE barrier per b

        // ---- P2: S^T = mfma(K,Q); +bias; in-register softmax
        f32x4 st[9];
        {
            bf16x8 qF = *(bf16x8*)&Qs[(m0 + lr) * 40 + lg * 8];
#pragma unroll
            for (int i = 0; i < 9; ++i) {
                bf16x8 aF = *(bf16x8*)&Ks[(i * 16 + lr) * 40 + lg * 8];
                st[i] = __builtin_amdgcn_mfma_f32_16x16x32_bf16(aF, qF, zf, 0, 0, 0);
            }
            float mx = -3.0e38f;
#pragma unroll
            for (int i = 0; i < 9; ++i)
#pragma unroll
                for (int r = 0; r < 4; ++r) {
                    st[i][r] += (float)bb[i][r];
                    mx = fmaxf(mx, st[i][r]);
                }
            mx = fmaxf(mx, __shfl_xor(mx, 16));
            mx = fmaxf(mx, __shfl_xor(mx, 32));
            float sum = 0.f;
#pragma unroll
            for (int i = 0; i < 9; ++i)
#pragma unroll
                for (int r = 0; r < 4; ++r) {
                    float e = __expf(st[i][r] - mx);
                    st[i][r] = e;
                    sum += e;
                }
            sum += __shfl_xor(sum, 16);
            sum += __shfl_xor(sum, 32);
            float inv = 1.f / sum;
#pragma unroll
            for (int i = 0; i < 9; ++i)
#pragma unroll
                for (int r = 0; r < 4; ++r) st[i][r] *= inv;
        }

        // ---- P3: O = P @ V via per-wave P scratch (overlay on Qs strip)
        __bf16* Pw = Qs + m0 * 40;     // [16][40] wave-private
        f32x4 o0 = zf, o1 = zf;
#pragma unroll
        for (int s = 0; s < 4; ++s) {
#pragma unroll
            for (int d = 0; d < 2; ++d) {
                int ii = 2 * s + d;
                bf16x4 pk;
#pragma unroll
                for (int r = 0; r < 4; ++r) pk[r] = (__bf16)st[ii][r];
                *(bf16x4*)&Pw[lr * 40 + d * 16 + lg * 4] = pk;
            }
            bf16x8 aP  = *(bf16x8*)&Pw[lr * 40 + lg * 8];
            bf16x8 v0F = *(bf16x8*)&Vt[lr * 152 + s * 32 + lg * 8];
            bf16x8 v1F = *(bf16x8*)&Vt[(16 + lr) * 152 + s * 32 + lg * 8];
            o0 = __builtin_amdgcn_mfma_f32_16x16x32_bf16(aP, v0F, o0, 0, 0, 0);
            o1 = __builtin_amdgcn_mfma_f32_16x16x32_bf16(aP, v1F, o1, 0, 0, 0);
        }
        {   // tail keys 128..143: lanes lg>=2 supply zeros
            bf16x4 pk;
#pragma unroll
            for (int r = 0; r < 4; ++r) pk[r] = (__bf16)st[8][r];
            *(bf16x4*)&Pw[lr * 40 + lg * 4] = pk;
            bf16x8 aP = zb, v0F = zb, v1F = zb;
            if (lg < 2) {
                aP  = *(bf16x8*)&Pw[lr * 40 + lg * 8];
                v0F = *(bf16x8*)&Vt[lr * 152 + 128 + lg * 8];
                v1F = *(bf16x8*)&Vt[(16 + lr) * 152 + 128 + lg * 8];
            }
            o0 = __builtin_amdgcn_mfma_f32_16x16x32_bf16(aP, v0F, o0, 0, 0, 0);
            o1 = __builtin_amdgcn_mfma_f32_16x16x32_bf16(aP, v1F, o1, 0, 0, 0);
        }

        // ---- O restage (coalesce) + store to opre[b][m][h*32..]
#pragma unroll
        for (int r = 0; r < 4; ++r) {
            Pw[(lg * 4 + r) * 40 + lr]      = (__bf16)o0[r];
            Pw[(lg * 4 + r) * 40 + 16 + lr] = (__bf16)o1[r];
        }
        {
            int l = tid & 63;
            int row = l >> 2, c = l & 3;
            bf16x8 ov = *(bf16x8*)&Pw[row * 40 + c * 8];
            *(bf16x8*)&opre[((size_t)b * SEQ + m0 + row) * DIM + h * HD + c * 8] = ov;
        }

        // ---- convert prefetched X -> aX
        if (nb < 7) {
#pragma unroll
            for (int kk = 0; kk < 6; ++kk) {
                f32x4 u = nx[2 * kk], v = nx[2 * kk + 1];
                bf16x8 t;
                t[0]=(__bf16)u[0]; t[1]=(__bf16)u[1]; t[2]=(__bf16)u[2]; t[3]=(__bf16)u[3];
                t[4]=(__bf16)v[0]; t[5]=(__bf16)v[1]; t[6]=(__bf16)v[2]; t[7]=(__bf16)v[3];
                aX[kk] = t;
            }
        }
    }
}

// ---------------------------------------------------------------------------
// Out-projection: out = opre @ w2 + b2.  W2 lives in REGISTERS (18 persistent
// B-frags per wave = its 48-col slice), loaded once; block loops 9 M-tiles of
// 16 rows with double-buffered LDS A-staging. 4 waves, LDS 12.8 KB.
// ---------------------------------------------------------------------------
__global__ __launch_bounds__(256, 3) void k_proj(
        const char* __restrict__ ws, const float* __restrict__ b2,
        float* __restrict__ out) {
    const __bf16* opre = (const __bf16*)(ws + WS_OPRE);
    const __bf16* w2t  = (const __bf16*)(ws + WS_W2T);
    __shared__ __bf16 As[2][16 * 200];

    const int tid = threadIdx.x;
    const int w = tid >> 6, lr = tid & 15, lg = (tid & 63) >> 4;
    const f32x4 zf = {0.f, 0.f, 0.f, 0.f};

    // persistent B-frags + bias for this wave's 48 cols
    bf16x8 bW[3][6];
    float bcol[3];
#pragma unroll
    for (int i = 0; i < 3; ++i) {
        int col = (w * 3 + i) * 16 + lr;
        bcol[i] = b2[col];
#pragma unroll
        for (int kk = 0; kk < 6; ++kk)
            bW[i][kk] = *(const bf16x8*)(w2t + (col * 192 + kk * 32 + lg * 8));
    }

    const int i0r = tid / 24,  i0c = tid % 24;          // chunk tid
    const int i1r = (tid + 256) / 24, i1c = (tid + 256) % 24;
    const bool has1 = tid < 128;

    // prologue: stage tile 0 into buf 0
    {
        size_t row0 = (size_t)blockIdx.x * 9 * 16;
        bf16x8 s0 = *(const bf16x8*)&opre[(row0 + i0r) * DIM + i0c * 8];
        *(bf16x8*)&As[0][i0r * 200 + i0c * 8] = s0;
        if (has1) {
            bf16x8 s1 = *(const bf16x8*)&opre[(row0 + i1r) * DIM + i1c * 8];
            *(bf16x8*)&As[0][i1r * 200 + i1c * 8] = s1;
        }
    }

    for (int t = 0; t < 9; ++t) {
        bf16x8 n0, n1;
        if (t < 8) {
            size_t rown = ((size_t)blockIdx.x * 9 + t + 1) * 16;
            n0 = *(const bf16x8*)&opre[(rown + i0r) * DIM + i0c * 8];
            if (has1) n1 = *(const bf16x8*)&opre[(rown + i1r) * DIM + i1c * 8];
        }
        __syncthreads();   // As[t&1] writes visible
        const __bf16* A = As[t & 1];
        f32x4 acc[3];
#pragma unroll
        for (int i = 0; i < 3; ++i) acc[i] = zf;
#pragma unroll
        for (int kk = 0; kk < 6; ++kk) {
            bf16x8 aF = *(const bf16x8*)&A[lr * 200 + kk * 32 + lg * 8];
#pragma unroll
            for (int i = 0; i < 3; ++i)
                acc[i] = __builtin_amdgcn_mfma_f32_16x16x32_bf16(aF, bW[i][kk], acc[i], 0, 0, 0);
        }
        size_t row0 = ((size_t)blockIdx.x * 9 + t) * 16;
#pragma unroll
        for (int i = 0; i < 3; ++i) {
            int col = (w * 3 + i) * 16 + lr;
#pragma unroll
            for (int r = 0; r < 4; ++r)
                out[(row0 + lg * 4 + r) * DIM + col] = acc[i][r] + bcol[i];
        }
        if (t < 8) {
            *(bf16x8*)&As[(t + 1) & 1][i0r * 200 + i0c * 8] = n0;
            if (has1) *(bf16x8*)&As[(t + 1) & 1][i1r * 200 + i1c * 8] = n1;
        }
    }
}

// ---------------------------------------------------------------------------
extern "C" void kernel_launch(void* const* d_in, const int* in_sizes, int n_in,
                              void* d_out, int out_size, void* d_ws, size_t ws_size,
                              hipStream_t stream) {
    const float* x    = (const float*)d_in[0];
    const float* w1   = (const float*)d_in[1];
    const float* b1   = (const float*)d_in[2];
    const float* w2   = (const float*)d_in[3];
    const float* b2   = (const float*)d_in[4];
    const float* bt   = (const float*)d_in[5];
    const int*   pidx = (const int*)d_in[6];
    const int*   mask = (const int*)d_in[7];
    float* out = (float*)d_out;
    char*  ws  = (char*)d_ws;

    k_prep<<<658, 256, 0, stream>>>(w1, w2, b1, bt, pidx, mask, ws);
    k_attn<<<768, 576, 0, stream>>>(x, ws);
    k_proj<<<1024, 256, 0, stream>>>(ws, b2, out);
}